// Round 10
// baseline (132.942 us; speedup 1.0000x reference)
//
#include <hip/hip_runtime.h>
#include <hip/hip_bf16.h>

// NT-Xent loss: z1,z2 [4096,256] fp32 -> scalar loss.
// R14: R12's cross-tile B double-buffer with the register budget FIXED.
// R12 crashed because __launch_bounds__(512,4) caps VGPR at 128 while the
// live set (BfrA+BfrB 128 + acc 32 + afc/afn 32 + rs 16 + addr) is ~223 —
// the allocator cannot keep 16 in-flight asm-load destinations live under
// that cap (spilling an in-flight asm output is semantically broken).
// Fix: __launch_bounds__(512,2) -> 256-reg cap; 223 fits; per-SIMD
// 2 waves x 223 = 446 <= 512 pool. 1 block/CU, ILP replaces TLP.
// Pipeline (unchanged from R12): issue tile t+1's 16 opaque B loads, then
// s_waitcnt vmcnt(16) retires exactly tile t's loads while t+1's fly under
// the whole k-loop. Static BfrA/BfrB, 2-tile loop body (rule #20).
// Kept: full-matrix row-streamed structure (R11), A staged once, one row
// flush, XOR-swizzled A, sched_barrier after waitcnt (rule #18).

#define TWO_N 8192
#define NPAIR 4096
#define DDIM  256
#define NT    64                    // 128-row tiles per dim
#define INV_T 2.0f

typedef __attribute__((ext_vector_type(8))) short bf16x8;
typedef __attribute__((ext_vector_type(4))) float f32x4;

typedef __attribute__((address_space(1))) void gvoid_t;
typedef __attribute__((address_space(3))) void lvoid_t;

__device__ __forceinline__ void gload_lds16(const void* g, void* l) {
    __builtin_amdgcn_global_load_lds((gvoid_t*)g, (lvoid_t*)l, 16, 0, 0);
}

// ---------------- Kernel 1: normalize + quantize + pair-dot + zero scratch --
// grid 1024 x 256: one wave per PAIR i (handles rows i and i+4096).
__global__ void k_normalize(const float* __restrict__ z1,
                            const float* __restrict__ z2,
                            __hip_bfloat16* __restrict__ zn,
                            float* __restrict__ e_diag,
                            float* __restrict__ pos,
                            float* __restrict__ row_sumexp,
                            float* __restrict__ out) {
    if (threadIdx.x < 8) row_sumexp[blockIdx.x * 8 + threadIdx.x] = 0.0f;
    if (blockIdx.x == 0 && threadIdx.x == 0) out[0] = 0.0f;

    const int w    = threadIdx.x >> 6;
    const int lane = threadIdx.x & 63;
    const int i    = blockIdx.x * 4 + w;

    float4 a = ((const float4*)(z1 + (size_t)i * DDIM))[lane];
    float4 b = ((const float4*)(z2 + (size_t)i * DDIM))[lane];

    float s1 = a.x * a.x + a.y * a.y + a.z * a.z + a.w * a.w;
    float s2 = b.x * b.x + b.y * b.y + b.z * b.z + b.w * b.w;
    float dd = a.x * b.x + a.y * b.y + a.z * b.z + a.w * b.w;
#pragma unroll
    for (int m = 1; m < 64; m <<= 1) {
        s1 += __shfl_xor(s1, m, 64);
        s2 += __shfl_xor(s2, m, 64);
        dd += __shfl_xor(dd, m, 64);
    }

    float inv1 = 1.0f / fmaxf(sqrtf(s1), 1e-8f);   // matches reference eps
    float inv2 = 1.0f / fmaxf(sqrtf(s2), 1e-8f);

    __hip_bfloat16 q1[4], q2[4];
    q1[0] = __float2bfloat16(a.x * inv1); q1[1] = __float2bfloat16(a.y * inv1);
    q1[2] = __float2bfloat16(a.z * inv1); q1[3] = __float2bfloat16(a.w * inv1);
    q2[0] = __float2bfloat16(b.x * inv2); q2[1] = __float2bfloat16(b.y * inv2);
    q2[2] = __float2bfloat16(b.z * inv2); q2[3] = __float2bfloat16(b.w * inv2);

    float qs1 = 0.0f, qs2 = 0.0f;
#pragma unroll
    for (int j = 0; j < 4; ++j) {
        float f1 = __bfloat162float(q1[j]);
        float f2 = __bfloat162float(q2[j]);
        qs1 += f1 * f1;
        qs2 += f2 * f2;
    }
#pragma unroll
    for (int m = 1; m < 64; m <<= 1) {
        qs1 += __shfl_xor(qs1, m, 64);
        qs2 += __shfl_xor(qs2, m, 64);
    }

    *reinterpret_cast<uint2*>(zn + (size_t)i * DDIM + lane * 4) =
        *reinterpret_cast<uint2*>(q1);
    *reinterpret_cast<uint2*>(zn + (size_t)(i + NPAIR) * DDIM + lane * 4) =
        *reinterpret_cast<uint2*>(q2);

    if (lane == 0) {
        e_diag[i]         = __expf(qs1 * INV_T);   // matches GEMM's bf16 self-dot
        e_diag[i + NPAIR] = __expf(qs2 * INV_T);
        pos[i]            = dd * inv1 * inv2 * INV_T;  // positive-pair term, fp32
    }
}

// ---------------- Kernel 2: full-matrix row-streamed GEMM, pipelined B ------
// 512 blocks x 512 threads (8 waves, 2x4 over a 128x128 tile).
// block: panel = bid>>3 (rows), chunk = bid&7 (cols chunk*1024..+1023).
// A staged once; 8 tiles; B double-buffered across tiles with vmcnt(16).
__global__ __launch_bounds__(512, 2)   // 256-reg cap; live set ~223 fits
void k_gemm_rows(const __hip_bfloat16* __restrict__ zn,
                 float* __restrict__ row_sumexp) {
    __shared__ __align__(128) __hip_bfloat16 Asmem[128 * DDIM];   // 64 KB

    const int tid  = threadIdx.x;
    const int lane = tid & 63;
    const int w    = tid >> 6;
    const int wr   = w >> 2;          // 0/1: rows wr*64..+64
    const int wc   = w & 3;           // 0..3: cols wc*32..+32
    const int lr   = lane & 15;
    const int quad = lane >> 4;

    const int panel    = blockIdx.x >> 3;       // 0..63
    const int chunk    = blockIdx.x & 7;        // 0..7
    const int row_base = panel * 128;

    // --- stage A panel ONCE (XOR-swizzled, 8 x gload_lds16/thread) ---
    {
        const int ck = (tid & 24) | ((tid & 7) ^ ((tid >> 5) & 7));
        const char* gA = (const char*)(zn + (size_t)row_base * DDIM)
                       + (tid >> 5) * (DDIM * 2) + ck * 16;
        char* lA = (char*)Asmem + tid * 16;
#pragma unroll
        for (int j = 0; j < 8; ++j)
            gload_lds16(gA + (size_t)j * 16 * (DDIM * 2), lA + j * 8192);
    }

    // --- A fragment LDS byte offsets (swizzled; verified R3-R11) ---
    int pa[4];
#pragma unroll
    for (int mi = 0; mi < 4; ++mi)
        pa[mi] = (wr * 64 + mi * 16 + lr) * (DDIM * 2) + ((quad ^ (lr & 7)) << 4);

    const __hip_bfloat16* gBw = zn + (size_t)(wc * 32 + lr) * DDIM + quad * 8;

    f32x4 acc[4][2];
    float rs[4][4];
#pragma unroll
    for (int mi = 0; mi < 4; ++mi)
#pragma unroll
        for (int r = 0; r < 4; ++r) rs[mi][r] = 0.0f;

    bf16x8 BfrA[8][2], BfrB[8][2];

    // issue one tile's 16 opaque B loads into the given (static) buffer
    auto issueB = [&](bf16x8 (&B)[8][2], int tt) {
        const __hip_bfloat16* gB0 = gBw + (size_t)(chunk * 8 + tt) * 128 * DDIM;
#pragma unroll
        for (int ks = 0; ks < 8; ++ks) {
            const __hip_bfloat16* p0 = gB0 + ks * 32;
            const __hip_bfloat16* p1 = p0 + 16 * DDIM;
            asm volatile("global_load_dwordx4 %0, %1, off"
                         : "=v"(B[ks][0]) : "v"(p0) : "memory");
            asm volatile("global_load_dwordx4 %0, %1, off"
                         : "=v"(B[ks][1]) : "v"(p1) : "memory");
        }
    };

    // exp + accumulate the just-finished tile's acc into rs. Pure VALU.
    auto epi_accum = [&]() {
#pragma unroll
        for (int mi = 0; mi < 4; ++mi)
#pragma unroll
            for (int r = 0; r < 4; ++r) {
                rs[mi][r] += __expf(acc[mi][0][r] * INV_T)
                           + __expf(acc[mi][1][r] * INV_T);
            }
    };

    // pure LDS+register k-loop on the given (static) buffer
    auto kloop = [&](bf16x8 (&B)[8][2]) {
#pragma unroll
        for (int mi = 0; mi < 4; ++mi)
#pragma unroll
            for (int ni = 0; ni < 2; ++ni)
                acc[mi][ni] = (f32x4){0.f, 0.f, 0.f, 0.f};
        bf16x8 afc[4];
#pragma unroll
        for (int mi = 0; mi < 4; ++mi)
            afc[mi] = *(const bf16x8*)((const char*)Asmem + pa[mi]);
#pragma unroll
        for (int kstep = 0; kstep < 8; ++kstep) {
            bf16x8 afn[4];
            if (kstep < 7) {
                const int kn   = kstep + 1;
                const int koff = (kn >> 1) << 7;
                const int kx   = (kn & 1) << 6;
#pragma unroll
                for (int mi = 0; mi < 4; ++mi)
                    afn[mi] = *(const bf16x8*)((const char*)Asmem + ((pa[mi] ^ kx) + koff));
            }
#pragma unroll
            for (int mi = 0; mi < 4; ++mi)
#pragma unroll
                for (int ni = 0; ni < 2; ++ni)
                    acc[mi][ni] = __builtin_amdgcn_mfma_f32_16x16x32_bf16(
                        afc[mi], B[kstep][ni], acc[mi][ni], 0, 0, 0);
            if (kstep < 7) {
#pragma unroll
                for (int mi = 0; mi < 4; ++mi) afc[mi] = afn[mi];
            }
        }
    };

    // --- prologue: B(0) issued with A staging; one vmcnt(0) + barrier ---
    issueB(BfrA, 0);
    asm volatile("s_waitcnt vmcnt(0)" ::: "memory");
    __syncthreads();
    __builtin_amdgcn_sched_barrier(0);

    // --- steady state: 4 iterations x 2 tiles, counted vmcnt(16) ---
#pragma unroll 1
    for (int p = 0; p < 4; ++p) {
        const int te = 2 * p;

        issueB(BfrB, te + 1);                 // odd tile's loads in flight
        if (p > 0) epi_accum();               // exp(prev odd) under latency
        asm volatile("s_waitcnt vmcnt(16)" ::: "memory");   // BfrA ready
        __builtin_amdgcn_sched_barrier(0);
        kloop(BfrA);                          // tile te; BfrB flying under it

        if (te + 2 < 8) issueB(BfrA, te + 2); // next even tile's loads
        epi_accum();                          // exp(te) under latency
        if (te + 2 < 8) {
            asm volatile("s_waitcnt vmcnt(16)" ::: "memory");   // BfrB ready
        } else {
            asm volatile("s_waitcnt vmcnt(0)" ::: "memory");    // drain last
        }
        __builtin_amdgcn_sched_barrier(0);
        kloop(BfrB);                          // tile te+1
    }

    epi_accum();   // last tile (t7)

    // --- single row flush: the only atomics in the kernel.
    //     C/D layout (verified): col = lane&15, row = quad*4 + reg. ---
#pragma unroll
    for (int mi = 0; mi < 4; ++mi) {
#pragma unroll
        for (int r = 0; r < 4; ++r) {
            float v = rs[mi][r];
            v += __shfl_xor(v, 1, 64);
            v += __shfl_xor(v, 2, 64);
            v += __shfl_xor(v, 4, 64);
            v += __shfl_xor(v, 8, 64);
            if (lr == 0)
                atomicAdd(&row_sumexp[row_base + wr * 64 + mi * 16 + quad * 4 + r], v);
        }
    }
}

// ---------------- Kernel 3: tiny finisher ----------------
// grid 16 x 256: one thread per pair index.
__global__ void k_final(const float* __restrict__ row_sumexp,
                        const float* __restrict__ e_diag,
                        const float* __restrict__ pos,
                        float* __restrict__ out) {
    const int i    = blockIdx.x * 256 + threadIdx.x;   // 0..4095
    const int w    = threadIdx.x >> 6;
    const int lane = threadIdx.x & 63;

    float t = logf(row_sumexp[i] - e_diag[i])
            + logf(row_sumexp[i + NPAIR] - e_diag[i + NPAIR])
            - 2.0f * pos[i];
#pragma unroll
    for (int m = 1; m < 64; m <<= 1) t += __shfl_xor(t, m, 64);

    __shared__ float ps[4];
    if (lane == 0) ps[w] = t;
    __syncthreads();
    if (threadIdx.x == 0) {
        float s = (ps[0] + ps[1] + ps[2] + ps[3]) * (1.0f / (float)TWO_N);
        atomicAdd(out, s);
    }
}

extern "C" void kernel_launch(void* const* d_in, const int* in_sizes, int n_in,
                              void* d_out, int out_size, void* d_ws, size_t ws_size,
                              hipStream_t stream) {
    const float* z1 = (const float*)d_in[0];
    const float* z2 = (const float*)d_in[1];
    float* out = (float*)d_out;

    char* ws = (char*)d_ws;
    __hip_bfloat16* zn  = (__hip_bfloat16*)ws;                       // 4 MB
    float* row_sumexp   = (float*)(ws + (size_t)TWO_N * DDIM * 2);   // 32 KB
    float* e_diag       = row_sumexp + TWO_N;                        // 32 KB
    float* pos          = e_diag + TWO_N;                            // 16 KB

    k_normalize<<<NPAIR / 4, 256, 0, stream>>>(z1, z2, zn, e_diag, pos,
                                               row_sumexp, out);
    k_gemm_rows<<<NT * 8, 512, 0, stream>>>(zn, row_sumexp);
    k_final<<<NPAIR / 256, 256, 0, stream>>>(row_sumexp, e_diag, pos, out);
}

// Round 11
// 124.793 us; speedup vs baseline: 1.0653x; 1.0653x over previous
//
#include <hip/hip_runtime.h>
#include <hip/hip_bf16.h>

// NT-Xent loss: z1,z2 [4096,256] fp32 -> scalar loss.
// R15: REVERSION to the session-best configuration (R5, 125.6us total,
// gemm 65.3us). Rationale: rounds R6-R14 falsified every throughput theory --
// wall time is invariant (65-77us) under 2x MFMA work (triangle vs full
// matrix), block count 256..2080, occupancy 1-2 blocks/CU, and pipeline
// depth (R11 serial == R14 pipelined, bit-identical 76.6us). All pipes
// measure <30% of ceiling; the evidence indicates a work-insensitive
// latency/clock floor in the gemm phase plus ~55us harness-fixed overhead
// (survives full fusion, R10). Under that model further structural churn has
// negative expected value; restore the best measured point.
// Structure: triangle (2080 tiles, 1 tile/block, 256 thr), full-K A tile in
// LDS (XOR-swizzled, global_load_lds), B streamed from L2 with compiler-
// scheduled 1-step prefetch, fused exp + row/col sums, XCD chunk swizzle,
// pair-dot folded into k_normalize.

#define TWO_N 8192
#define NPAIR 4096
#define DDIM  256
#define NT    64                    // 128-row tiles per dim
#define NBLK  (NT * (NT + 1) / 2)   // 2080 upper-triangle tiles
#define INV_T 2.0f

typedef __attribute__((ext_vector_type(8))) short bf16x8;
typedef __attribute__((ext_vector_type(4))) float f32x4;

typedef __attribute__((address_space(1))) void gvoid_t;
typedef __attribute__((address_space(3))) void lvoid_t;

__device__ __forceinline__ void gload_lds16(const void* g, void* l) {
    __builtin_amdgcn_global_load_lds((gvoid_t*)g, (lvoid_t*)l, 16, 0, 0);
}

// ---------------- Kernel 1: normalize + quantize + pair-dot + zero scratch --
// grid 1024 x 256: one wave per PAIR i (handles rows i and i+4096).
__global__ void k_normalize(const float* __restrict__ z1,
                            const float* __restrict__ z2,
                            __hip_bfloat16* __restrict__ zn,
                            float* __restrict__ e_diag,
                            float* __restrict__ pos,
                            float* __restrict__ row_sumexp,
                            float* __restrict__ out) {
    if (threadIdx.x < 8) row_sumexp[blockIdx.x * 8 + threadIdx.x] = 0.0f;
    if (blockIdx.x == 0 && threadIdx.x == 0) out[0] = 0.0f;

    const int w    = threadIdx.x >> 6;
    const int lane = threadIdx.x & 63;
    const int i    = blockIdx.x * 4 + w;

    float4 a = ((const float4*)(z1 + (size_t)i * DDIM))[lane];
    float4 b = ((const float4*)(z2 + (size_t)i * DDIM))[lane];

    float s1 = a.x * a.x + a.y * a.y + a.z * a.z + a.w * a.w;
    float s2 = b.x * b.x + b.y * b.y + b.z * b.z + b.w * b.w;
    float dd = a.x * b.x + a.y * b.y + a.z * b.z + a.w * b.w;
#pragma unroll
    for (int m = 1; m < 64; m <<= 1) {
        s1 += __shfl_xor(s1, m, 64);
        s2 += __shfl_xor(s2, m, 64);
        dd += __shfl_xor(dd, m, 64);
    }

    float inv1 = 1.0f / fmaxf(sqrtf(s1), 1e-8f);   // matches reference eps
    float inv2 = 1.0f / fmaxf(sqrtf(s2), 1e-8f);

    __hip_bfloat16 q1[4], q2[4];
    q1[0] = __float2bfloat16(a.x * inv1); q1[1] = __float2bfloat16(a.y * inv1);
    q1[2] = __float2bfloat16(a.z * inv1); q1[3] = __float2bfloat16(a.w * inv1);
    q2[0] = __float2bfloat16(b.x * inv2); q2[1] = __float2bfloat16(b.y * inv2);
    q2[2] = __float2bfloat16(b.z * inv2); q2[3] = __float2bfloat16(b.w * inv2);

    float qs1 = 0.0f, qs2 = 0.0f;
#pragma unroll
    for (int j = 0; j < 4; ++j) {
        float f1 = __bfloat162float(q1[j]);
        float f2 = __bfloat162float(q2[j]);
        qs1 += f1 * f1;
        qs2 += f2 * f2;
    }
#pragma unroll
    for (int m = 1; m < 64; m <<= 1) {
        qs1 += __shfl_xor(qs1, m, 64);
        qs2 += __shfl_xor(qs2, m, 64);
    }

    *reinterpret_cast<uint2*>(zn + (size_t)i * DDIM + lane * 4) =
        *reinterpret_cast<uint2*>(q1);
    *reinterpret_cast<uint2*>(zn + (size_t)(i + NPAIR) * DDIM + lane * 4) =
        *reinterpret_cast<uint2*>(q2);

    if (lane == 0) {
        e_diag[i]         = __expf(qs1 * INV_T);   // matches GEMM's bf16 self-dot
        e_diag[i + NPAIR] = __expf(qs2 * INV_T);
        pos[i]            = dd * inv1 * inv2 * INV_T;  // positive-pair term, pure fp32
    }
}

// ---------------- Kernel 2: symmetric MFMA self-GEMM + exp + row/col sums ----
// 2080 blocks (upper-triangle 128x128 tiles), 256 threads (2x2 waves of 64x64).
// A-tile full K in LDS (swizzled), staged with global_load_lds(16B).
// B panel prefetched into registers (compiler-scheduled; pins are no-ops but
// kept to byte-match the best-measured R5 binary).
__global__ __launch_bounds__(256, 2)
void k_gemm_sumexp(const __hip_bfloat16* __restrict__ zn,
                   float* __restrict__ row_sumexp) {
    __shared__ __align__(128) __hip_bfloat16 Asmem[128 * DDIM];   // 64 KB

    const int tid  = threadIdx.x;
    const int lane = tid & 63;
    const int w    = tid >> 6;
    const int wr   = w >> 1;          // wave row-half (0/1)
    const int wc   = w & 1;           // wave col-half (0/1)
    const int lr   = lane & 15;
    const int quad = lane >> 4;

    // --- XCD chunk swizzle: 2080 = 8*260 exactly, bijective. ---
    int b = (blockIdx.x & 7) * (NBLK / 8) + (blockIdx.x >> 3);

    // --- triangular decode: block b -> (rt, ct), rt <= ct (verified R2) ---
    int rt = (int)(64.5f - sqrtf(64.5f * 64.5f - 2.0f * (float)b));
    if (rt < 0) rt = 0;
    if (rt > NT - 1) rt = NT - 1;
    while (rt > 0 && NT * rt - (rt * (rt - 1)) / 2 > b) --rt;
    while (NT * (rt + 1) - ((rt + 1) * rt) / 2 <= b) ++rt;
    const int ct   = rt + (b - (NT * rt - (rt * (rt - 1)) / 2));
    const bool diag = (rt == ct);

    const int row_base = rt * 128;
    const int col_base = ct * 128;

    // --- stage A tile FIRST: slot s = j*256+tid -> row = j*8 + (tid>>5),
    //     c' = tid&31; source chunk ck per-thread constant. 16 x 16B/lane. ---
    {
        const int ck = (tid & 24) | ((tid & 7) ^ (tid >> 5));
        const char* gA = (const char*)(zn + (size_t)row_base * DDIM)
                       + (tid >> 5) * (DDIM * 2) + ck * 16;
        char* lA = (char*)Asmem + tid * 16;
#pragma unroll
        for (int j = 0; j < 16; ++j)
            gload_lds16(gA + (size_t)j * 8 * (DDIM * 2), lA + j * 4096);
    }

    // --- B fragment global pointers: row = col_base + wc*64 + ni*16 + lr ---
    const __hip_bfloat16* gB[4];
#pragma unroll
    for (int ni = 0; ni < 4; ++ni)
        gB[ni] = zn + (size_t)(col_base + wc * 64 + ni * 16 + lr) * DDIM + quad * 8;

    // --- issue the FULL B panel into registers: 32 x 16B per lane ---
    bf16x8 Bfr[8][4];
#pragma unroll
    for (int ks = 0; ks < 8; ++ks)
#pragma unroll
        for (int ni = 0; ni < 4; ++ni)
            Bfr[ks][ni] = *(const bf16x8*)(gB[ni] + ks * 32);

    // --- pin attempt (measured no-op; kept to match the 125.6us binary) ---
#pragma unroll
    for (int ks = 0; ks < 8; ++ks)
#pragma unroll
        for (int ni = 0; ni < 4; ++ni)
            asm volatile("" : "+v"(Bfr[ks][ni]));

    __syncthreads();   // the ONLY barrier (drains the A staging)

    // --- A fragment LDS byte offsets (swizzled) ---
    // A(mi,kstep): row = wr*64+mi*16+lr, byte = row*512 + (kstep>>1)*128
    //              + [ (quad ^ (lr&7)) ^ ((kstep&1)<<2) ] * 16
    int pa[4];
#pragma unroll
    for (int mi = 0; mi < 4; ++mi)
        pa[mi] = (wr * 64 + mi * 16 + lr) * (DDIM * 2) + ((quad ^ (lr & 7)) << 4);

    f32x4 acc[4][4];
#pragma unroll
    for (int mi = 0; mi < 4; ++mi)
#pragma unroll
        for (int ni = 0; ni < 4; ++ni) acc[mi][ni] = (f32x4){0.f, 0.f, 0.f, 0.f};

    bf16x8 afc[4];
#pragma unroll
    for (int mi = 0; mi < 4; ++mi)
        afc[mi] = *(const bf16x8*)((const char*)Asmem + pa[mi]);

#pragma unroll
    for (int kstep = 0; kstep < 8; ++kstep) {
        bf16x8 afn[4];
        if (kstep < 7) {
            const int kn   = kstep + 1;
            const int koff = ((kn >> 1) << 7);
            const int kx   = ((kn & 1) << 6);
#pragma unroll
            for (int mi = 0; mi < 4; ++mi)
                afn[mi] = *(const bf16x8*)((const char*)Asmem + ((pa[mi] ^ kx) + koff));
        }
#pragma unroll
        for (int mi = 0; mi < 4; ++mi)
#pragma unroll
            for (int ni = 0; ni < 4; ++ni)
                acc[mi][ni] = __builtin_amdgcn_mfma_f32_16x16x32_bf16(
                    afc[mi], Bfr[kstep][ni], acc[mi][ni], 0, 0, 0);
        if (kstep < 7) {
#pragma unroll
            for (int mi = 0; mi < 4; ++mi) afc[mi] = afn[mi];
        }
    }

    // --- epilogue: e = exp(2*dot); row-sums always, col-sums if off-diag ---
    // C/D layout (verified R1/R2): col = lane&15, row = quad*4 + reg.
    float rs[4][4];
    float cs[4];
#pragma unroll
    for (int mi = 0; mi < 4; ++mi)
#pragma unroll
        for (int r = 0; r < 4; ++r) rs[mi][r] = 0.0f;
#pragma unroll
    for (int ni = 0; ni < 4; ++ni) cs[ni] = 0.0f;

#pragma unroll
    for (int mi = 0; mi < 4; ++mi)
#pragma unroll
        for (int ni = 0; ni < 4; ++ni)
#pragma unroll
            for (int r = 0; r < 4; ++r) {
                float e = __expf(acc[mi][ni][r] * INV_T);
                rs[mi][r] += e;
                cs[ni] += e;
            }

    // row sums: reduce over lane bits 0..3 (the 16 columns)
#pragma unroll
    for (int mi = 0; mi < 4; ++mi) {
#pragma unroll
        for (int r = 0; r < 4; ++r) {
            float v = rs[mi][r];
            v += __shfl_xor(v, 1, 64);
            v += __shfl_xor(v, 2, 64);
            v += __shfl_xor(v, 4, 64);
            v += __shfl_xor(v, 8, 64);
            if (lr == 0) {
                int row = row_base + wr * 64 + mi * 16 + quad * 4 + r;
                atomicAdd(&row_sumexp[row], v);
            }
        }
    }

    // col sums: reduce over lane bits 4..5
    if (!diag) {
#pragma unroll
        for (int ni = 0; ni < 4; ++ni) {
            float v = cs[ni];
            v += __shfl_xor(v, 16, 64);
            v += __shfl_xor(v, 32, 64);
            if (quad == 0) {
                int col = col_base + wc * 64 + ni * 16 + lr;
                atomicAdd(&row_sumexp[col], v);
            }
        }
    }
}

// ---------------- Kernel 3: tiny finisher ----------------
// grid 16 x 256: one thread per pair index.
__global__ void k_final(const float* __restrict__ row_sumexp,
                        const float* __restrict__ e_diag,
                        const float* __restrict__ pos,
                        float* __restrict__ out) {
    const int i    = blockIdx.x * 256 + threadIdx.x;   // 0..4095
    const int w    = threadIdx.x >> 6;
    const int lane = threadIdx.x & 63;

    float t = logf(row_sumexp[i] - e_diag[i])
            + logf(row_sumexp[i + NPAIR] - e_diag[i + NPAIR])
            - 2.0f * pos[i];
#pragma unroll
    for (int m = 1; m < 64; m <<= 1) t += __shfl_xor(t, m, 64);

    __shared__ float ps[4];
    if (lane == 0) ps[w] = t;
    __syncthreads();
    if (threadIdx.x == 0) {
        float s = (ps[0] + ps[1] + ps[2] + ps[3]) * (1.0f / (float)TWO_N);
        atomicAdd(out, s);
    }
}

extern "C" void kernel_launch(void* const* d_in, const int* in_sizes, int n_in,
                              void* d_out, int out_size, void* d_ws, size_t ws_size,
                              hipStream_t stream) {
    const float* z1 = (const float*)d_in[0];
    const float* z2 = (const float*)d_in[1];
    float* out = (float*)d_out;

    char* ws = (char*)d_ws;
    __hip_bfloat16* zn  = (__hip_bfloat16*)ws;                       // 4 MB
    float* row_sumexp   = (float*)(ws + (size_t)TWO_N * DDIM * 2);   // 32 KB
    float* e_diag       = row_sumexp + TWO_N;                        // 32 KB
    float* pos          = e_diag + TWO_N;                            // 16 KB

    k_normalize<<<NPAIR / 4, 256, 0, stream>>>(z1, z2, zn, e_diag, pos,
                                               row_sumexp, out);
    k_gemm_sumexp<<<NBLK, 256, 0, stream>>>(zn, row_sumexp);
    k_final<<<NPAIR / 256, 256, 0, stream>>>(row_sumexp, e_diag, pos, out);
}